// Round 5
// baseline (152.720 us; speedup 1.0000x reference)
//
#include <hip/hip_runtime.h>
#include <hip/hip_bf16.h>

#define WIN   9
#define NB    8
#define LL    4096
#define CC    256
#define UU    256
#define NW    (LL - WIN + 1)   // 4088
#define MROWS (NB * LL)        // 32768

typedef unsigned short ushort;
typedef __attribute__((ext_vector_type(8))) unsigned short ushort8v;
typedef __attribute__((ext_vector_type(4))) unsigned short ushort4v;
typedef __attribute__((ext_vector_type(8))) short short8v;
typedef __attribute__((ext_vector_type(4))) float f32x4;

__device__ __forceinline__ float bf16_to_f(ushort u) {
    return __uint_as_float(((unsigned int)u) << 16);
}
__device__ __forceinline__ ushort f2bf(float f) {
    __hip_bfloat16 h = __float2bfloat16(f);
    return *reinterpret_cast<ushort*>(&h);
}
__device__ __forceinline__ float fast_tanh(float x) {
    float e = __expf(2.0f * x);
    return 1.0f - 2.0f * __builtin_amdgcn_rcpf(e + 1.0f);
}

// ---------------- P1: W [c][u] fp32 -> WT [u][c] bf16 ------------------------
__global__ __launch_bounds__(256) void transpose_w(const float* __restrict__ Wk,
                                                   const float* __restrict__ Wq,
                                                   ushort* __restrict__ WkT,
                                                   ushort* __restrict__ WqT) {
    const float* W = blockIdx.z ? Wq : Wk;
    ushort* O = blockIdx.z ? WqT : WkT;
    __shared__ float t[32][33];
    int c0 = blockIdx.x * 32, u0 = blockIdx.y * 32;
    int tr = threadIdx.x >> 3, tc = (threadIdx.x & 7) * 4;
    float4 v = *reinterpret_cast<const float4*>(&W[(size_t)(c0 + tr) * UU + u0 + tc]);
    t[tr][tc + 0] = v.x; t[tr][tc + 1] = v.y; t[tr][tc + 2] = v.z; t[tr][tc + 3] = v.w;
    __syncthreads();
    ushort4v o;
    #pragma unroll
    for (int i = 0; i < 4; ++i) o[i] = f2bf(t[tc + i][tr]);
    *reinterpret_cast<ushort4v*>(&O[(size_t)(u0 + tr) * CC + c0 + tc]) = o;
}

// ---------------- Kernel A: direct MFMA GEMM, no LDS -------------------------
// Everything is L2/L3-resident: load MFMA fragments straight from global.
// Grid: 256 blocks (M-tiles of 128 rows), 512 threads = 8 waves (2M x 4N).
// Wave tile 64(M) x 128(N); N=512 = [K cols 0-255 | Q cols 0-255].
// A comes from fp32 X with in-register bf16 conversion (cvt_x fused away).
__global__ __launch_bounds__(512) void gemm_direct(const float* __restrict__ X,
                                                   const ushort* __restrict__ WkT,
                                                   const ushort* __restrict__ WqT,
                                                   ushort* __restrict__ Kout,
                                                   ushort* __restrict__ Qout) {
    const int m0 = blockIdx.x * 128;
    const int wid = threadIdx.x >> 6, lane = threadIdx.x & 63;
    const int wr = wid >> 2;            // 0..1 : M half
    const int wc = wid & 3;             // 0..3 : 128-col slice of combined N=512
    const int lrow = lane & 15, lk = (lane >> 4) * 8;

    const ushort* WT = (wc < 2) ? WkT : WqT;
    ushort* Out = (wc < 2) ? Kout : Qout;
    const int nbase = (wc & 1) * 128;

    const float*  aBase = X  + (size_t)(m0 + wr * 64 + lrow) * CC + lk;
    const ushort* bBase = WT + (size_t)(nbase + lrow) * CC + lk;

    f32x4 acc[4][8] = {};

    #pragma unroll 2
    for (int k0 = 0; k0 < CC; k0 += 32) {
        short8v af[4], bf[8];
        #pragma unroll
        for (int m = 0; m < 4; ++m) {
            const float* p = aBase + (size_t)m * 16 * CC + k0;
            float4 a0 = *reinterpret_cast<const float4*>(p);
            float4 a1 = *reinterpret_cast<const float4*>(p + 4);
            ushort8v t;
            t[0] = f2bf(a0.x); t[1] = f2bf(a0.y); t[2] = f2bf(a0.z); t[3] = f2bf(a0.w);
            t[4] = f2bf(a1.x); t[5] = f2bf(a1.y); t[6] = f2bf(a1.z); t[7] = f2bf(a1.w);
            af[m] = *reinterpret_cast<short8v*>(&t);
        }
        #pragma unroll
        for (int n = 0; n < 8; ++n)
            bf[n] = *reinterpret_cast<const short8v*>(bBase + (size_t)n * 16 * CC + k0);
        #pragma unroll
        for (int m = 0; m < 4; ++m)
            #pragma unroll
            for (int n = 0; n < 8; ++n)
                acc[m][n] = __builtin_amdgcn_mfma_f32_16x16x32_bf16(af[m], bf[n], acc[m][n], 0, 0, 0);
    }

    // C layout: col = lane&15, row = (lane>>4)*4 + j
    const int orow0 = m0 + wr * 64 + (lane >> 4) * 4;
    const int ocol0 = nbase + lrow;
    #pragma unroll
    for (int m = 0; m < 4; ++m)
        #pragma unroll
        for (int n = 0; n < 8; ++n)
            #pragma unroll
            for (int j = 0; j < 4; ++j)
                Out[(size_t)(orow0 + m * 16 + j) * UU + ocol0 + n * 16] = f2bf(acc[m][n][j]);
}

// ---------------- Kernel B: score -> softmax -> weighted window sum ----------
// One wave per (n,w). Lane l owns u/c = 4l..4l+3. XCD-contiguous item remap.
__global__ __launch_bounds__(256) void attn_smooth(
    const float* __restrict__ X,
    const ushort* __restrict__ Kb,
    const ushort* __restrict__ Qb,
    const float* __restrict__ v,
    const float* __restrict__ b,
    float* __restrict__ out) {
    const int wave = threadIdx.x >> 6;
    const int lane = threadIdx.x & 63;
    // bijective remap: XCD j gets contiguous block range = exactly batch n=j
    const int bid = blockIdx.x;
    const int nb = (bid & 7) * 1022 + (bid >> 3);
    const int item = nb * 4 + wave;           // < 8*4088 = 32704 exactly
    const int n = item / NW;
    const int w = item % NW;
    const int u0 = lane * 4;

    const size_t rowbase = (size_t)(n * LL + w);

    float4 bv = *reinterpret_cast<const float4*>(&b[u0]);
    float4 vv = *reinterpret_cast<const float4*>(&v[u0]);

    ushort4 qu = *reinterpret_cast<const ushort4*>(&Qb[(rowbase + WIN / 2) * UU + u0]);
    float qb0 = bf16_to_f(qu.x) + bv.x;
    float qb1 = bf16_to_f(qu.y) + bv.y;
    float qb2 = bf16_to_f(qu.z) + bv.z;
    float qb3 = bf16_to_f(qu.w) + bv.w;

    float p[WIN];
    #pragma unroll
    for (int s = 0; s < WIN; ++s) {
        ushort4 ku = *reinterpret_cast<const ushort4*>(&Kb[(rowbase + s) * UU + u0]);
        float t;
        t  = vv.x * fast_tanh(qb0 + bf16_to_f(ku.x));
        t += vv.y * fast_tanh(qb1 + bf16_to_f(ku.y));
        t += vv.z * fast_tanh(qb2 + bf16_to_f(ku.z));
        t += vv.w * fast_tanh(qb3 + bf16_to_f(ku.w));
        p[s] = t;
    }
    #pragma unroll
    for (int off = 32; off; off >>= 1)
        #pragma unroll
        for (int s = 0; s < WIN; ++s)
            p[s] += __shfl_xor(p[s], off);

    float m = p[0];
    #pragma unroll
    for (int s = 1; s < WIN; ++s) m = fmaxf(m, p[s]);
    float e[WIN];
    float sum = 0.0f;
    #pragma unroll
    for (int s = 0; s < WIN; ++s) { e[s] = __expf(p[s] - m); sum += e[s]; }
    float inv = 1.0f / sum;

    float4 acc = {0.0f, 0.0f, 0.0f, 0.0f};
    #pragma unroll
    for (int s = 0; s < WIN; ++s) {
        float ws = e[s] * inv;
        float4 xv = *reinterpret_cast<const float4*>(&X[(rowbase + s) * CC + u0]);
        acc.x = fmaf(ws, xv.x, acc.x);
        acc.y = fmaf(ws, xv.y, acc.y);
        acc.z = fmaf(ws, xv.z, acc.z);
        acc.w = fmaf(ws, xv.w, acc.w);
    }
    *reinterpret_cast<float4*>(&out[((size_t)n * NW + w) * CC + u0]) = acc;
}

extern "C" void kernel_launch(void* const* d_in, const int* in_sizes, int n_in,
                              void* d_out, int out_size, void* d_ws, size_t ws_size,
                              hipStream_t stream) {
    const float* x  = (const float*)d_in[0];
    const float* Wq = (const float*)d_in[1];
    const float* Wk = (const float*)d_in[2];
    const float* v  = (const float*)d_in[3];
    const float* b  = (const float*)d_in[4];
    float* out = (float*)d_out;

    const size_t MU = (size_t)MROWS * UU;      // 8.39M elems
    ushort* Kbuf = (ushort*)d_ws;
    ushort* Qbuf = Kbuf + MU;
    ushort* WkT  = Qbuf + MU;
    ushort* WqT  = WkT + (size_t)CC * UU;

    transpose_w<<<dim3(8, 8, 2), 256, 0, stream>>>(Wk, Wq, WkT, WqT);
    gemm_direct<<<MROWS / 128, 512, 0, stream>>>(x, WkT, WqT, Kbuf, Qbuf);
    attn_smooth<<<(NB * NW) / 4, 256, 0, stream>>>(x, Kbuf, Qbuf, v, b, out);
}

// Round 6
// 145.680 us; speedup vs baseline: 1.0483x; 1.0483x over previous
//
#include <hip/hip_runtime.h>
#include <hip/hip_bf16.h>

#define WIN   9
#define NB    8
#define LL    4096
#define CC    256
#define UU    256
#define NW    (LL - WIN + 1)   // 4088
#define MROWS (NB * LL)        // 32768

#define BM 128
#define BK 64

typedef unsigned short ushort;
typedef __attribute__((ext_vector_type(8))) unsigned short ushort8v;
typedef __attribute__((ext_vector_type(4))) unsigned short ushort4v;
typedef __attribute__((ext_vector_type(8))) short short8v;
typedef __attribute__((ext_vector_type(4))) float f32x4;

__device__ __forceinline__ float bf16_to_f(ushort u) {
    return __uint_as_float(((unsigned int)u) << 16);
}
__device__ __forceinline__ ushort f2bf(float f) {
    __hip_bfloat16 h = __float2bfloat16(f);
    return *reinterpret_cast<ushort*>(&h);
}
__device__ __forceinline__ float fast_tanh(float x) {
    float e = __expf(2.0f * x);
    return 1.0f - 2.0f * __builtin_amdgcn_rcpf(e + 1.0f);
}

// ---------------- P0: X fp32 -> bf16 (reused by GEMM A and attn sum) ---------
__global__ __launch_bounds__(256) void cvt_x(const float* __restrict__ X,
                                             ushort* __restrict__ Xb) {
    size_t i = ((size_t)blockIdx.x * 256 + threadIdx.x) * 8;
    float4 v0 = *reinterpret_cast<const float4*>(X + i);
    float4 v1 = *reinterpret_cast<const float4*>(X + i + 4);
    ushort8v o;
    o[0] = f2bf(v0.x); o[1] = f2bf(v0.y); o[2] = f2bf(v0.z); o[3] = f2bf(v0.w);
    o[4] = f2bf(v1.x); o[5] = f2bf(v1.y); o[6] = f2bf(v1.z); o[7] = f2bf(v1.w);
    *reinterpret_cast<ushort8v*>(Xb + i) = o;
}

// ---------------- P1: W [c][u] fp32 -> WT [u][c] bf16 ------------------------
// WkT and WqT are CONTIGUOUS: combined [512][256] B^T for the GEMM.
__global__ __launch_bounds__(256) void transpose_w(const float* __restrict__ Wk,
                                                   const float* __restrict__ Wq,
                                                   ushort* __restrict__ WkT,
                                                   ushort* __restrict__ WqT) {
    const float* W = blockIdx.z ? Wq : Wk;
    ushort* O = blockIdx.z ? WqT : WkT;
    __shared__ float t[32][33];
    int c0 = blockIdx.x * 32, u0 = blockIdx.y * 32;
    int tr = threadIdx.x >> 3, tc = (threadIdx.x & 7) * 4;
    float4 v = *reinterpret_cast<const float4*>(&W[(size_t)(c0 + tr) * UU + u0 + tc]);
    t[tr][tc + 0] = v.x; t[tr][tc + 1] = v.y; t[tr][tc + 2] = v.z; t[tr][tc + 3] = v.w;
    __syncthreads();
    ushort4v o;
    #pragma unroll
    for (int i = 0; i < 4; ++i) o[i] = f2bf(t[tc + i][tr]);
    *reinterpret_cast<ushort4v*>(&O[(size_t)(u0 + tr) * CC + c0 + tc]) = o;
}

// ---------------- Kernel A: LDS MFMA GEMM via global_load_lds ---------------
// [K|Q] = Xb @ WT_all^T.  Combined N=512. Tile 128(M) x 128(N), BK=64.
// 256 thr = 4 waves (2Mx2N), wave tile 64x64, acc[4][4] f32x4.
// LDS linear [128][64] bf16; 16B-chunk XOR swizzle (c ^= row&7) applied to the
// GLOBAL source of global_load_lds and to the ds_read address (rule #21) ->
// every ds_read_b128 is 2-way (free), staging is linear DMA.
__global__ __launch_bounds__(256, 2) void gemm_lds(const ushort* __restrict__ Xb,
                                                   const ushort* __restrict__ WTall,
                                                   ushort* __restrict__ Kout,
                                                   ushort* __restrict__ Qout) {
    const int m0 = (blockIdx.x & 255) * BM;
    const int nt = blockIdx.x >> 8;          // 0..3 -> combined cols nt*128..+127
    const int n0 = nt * 128;

    __shared__ ushort As[BM * BK];
    __shared__ ushort Bs[BM * BK];

    const int tid = threadIdx.x;
    const int wid = tid >> 6, lane = tid & 63;
    const int wr = wid >> 1, wc = wid & 1;
    const int lrow = lane & 15;
    const int lkc  = lane >> 4;              // k-chunk (8 bf16) within 32-k half

    // per-lane staging geometry: issue i covers rows i*32 .. i*32+31
    const int srow_in_issue = wid * 8 + (lane >> 3);   // 0..31
    const int schunk = lane & 7;

    f32x4 acc[4][4] = {};

    for (int k0 = 0; k0 < CC; k0 += BK) {
        #pragma unroll
        for (int i = 0; i < 4; ++i) {
            int row = i * 32 + srow_in_issue;
            int ca  = schunk ^ (row & 7);
            const ushort* srcA = Xb    + (size_t)(m0 + row) * CC + k0 + ca * 8;
            const ushort* srcB = WTall + (size_t)(n0 + row) * CC + k0 + ca * 8;
            // wave-uniform LDS base; HW adds lane*16
            ushort* dstA = As + i * 2048 + wid * 512;
            ushort* dstB = Bs + i * 2048 + wid * 512;
            __builtin_amdgcn_global_load_lds(
                (const __attribute__((address_space(1))) void*)srcA,
                (__attribute__((address_space(3))) void*)dstA, 16, 0, 0);
            __builtin_amdgcn_global_load_lds(
                (const __attribute__((address_space(1))) void*)srcB,
                (__attribute__((address_space(3))) void*)dstB, 16, 0, 0);
        }
        __syncthreads();

        #pragma unroll
        for (int ks = 0; ks < 2; ++ks) {
            short8v af[4], bq[4];
            #pragma unroll
            for (int m = 0; m < 4; ++m) {
                int r = wr * 64 + m * 16 + lrow;
                int cc = ks * 4 + lkc;
                af[m] = *reinterpret_cast<const short8v*>(As + r * 64 + (cc ^ (r & 7)) * 8);
            }
            #pragma unroll
            for (int n = 0; n < 4; ++n) {
                int r = wc * 64 + n * 16 + lrow;
                int cc = ks * 4 + lkc;
                bq[n] = *reinterpret_cast<const short8v*>(Bs + r * 64 + (cc ^ (r & 7)) * 8);
            }
            #pragma unroll
            for (int m = 0; m < 4; ++m)
                #pragma unroll
                for (int n = 0; n < 4; ++n)
                    acc[m][n] = __builtin_amdgcn_mfma_f32_16x16x32_bf16(af[m], bq[n], acc[m][n], 0, 0, 0);
        }
        __syncthreads();
    }

    // C layout: col = lane&15, row = (lane>>4)*4 + j
    ushort* Out = (nt < 2) ? Kout : Qout;
    const int colbase = (nt & 1) * 128 + wc * 64;
    const int rowbase = m0 + wr * 64 + (lane >> 4) * 4;
    #pragma unroll
    for (int m = 0; m < 4; ++m)
        #pragma unroll
        for (int n = 0; n < 4; ++n)
            #pragma unroll
            for (int j = 0; j < 4; ++j)
                Out[(size_t)(rowbase + m * 16 + j) * UU + colbase + n * 16 + lrow] =
                    f2bf(acc[m][n][j]);
}

// ---------------- Kernel B: score -> softmax -> weighted window sum ----------
// One wave per (n,w). Lane l owns u/c = 4l..4l+3. XCD-contiguous item remap.
__global__ __launch_bounds__(256) void attn_smooth(
    const ushort* __restrict__ Xb,
    const ushort* __restrict__ Kb,
    const ushort* __restrict__ Qb,
    const float* __restrict__ v,
    const float* __restrict__ b,
    float* __restrict__ out) {
    const int wave = threadIdx.x >> 6;
    const int lane = threadIdx.x & 63;
    const int bid = blockIdx.x;
    const int nb = (bid & 7) * 1022 + (bid >> 3);
    const int item = nb * 4 + wave;           // < 8*4088 = 32704 exactly
    const int n = item / NW;
    const int w = item % NW;
    const int u0 = lane * 4;

    const size_t rowbase = (size_t)(n * LL + w);

    float4 bv = *reinterpret_cast<const float4*>(&b[u0]);
    float4 vv = *reinterpret_cast<const float4*>(&v[u0]);

    ushort4 qu = *reinterpret_cast<const ushort4*>(&Qb[(rowbase + WIN / 2) * UU + u0]);
    float qb0 = bf16_to_f(qu.x) + bv.x;
    float qb1 = bf16_to_f(qu.y) + bv.y;
    float qb2 = bf16_to_f(qu.z) + bv.z;
    float qb3 = bf16_to_f(qu.w) + bv.w;

    float p[WIN];
    #pragma unroll
    for (int s = 0; s < WIN; ++s) {
        ushort4 ku = *reinterpret_cast<const ushort4*>(&Kb[(rowbase + s) * UU + u0]);
        float t;
        t  = vv.x * fast_tanh(qb0 + bf16_to_f(ku.x));
        t += vv.y * fast_tanh(qb1 + bf16_to_f(ku.y));
        t += vv.z * fast_tanh(qb2 + bf16_to_f(ku.z));
        t += vv.w * fast_tanh(qb3 + bf16_to_f(ku.w));
        p[s] = t;
    }
    #pragma unroll
    for (int off = 32; off; off >>= 1)
        #pragma unroll
        for (int s = 0; s < WIN; ++s)
            p[s] += __shfl_xor(p[s], off);

    float m = p[0];
    #pragma unroll
    for (int s = 1; s < WIN; ++s) m = fmaxf(m, p[s]);
    float e[WIN];
    float sum = 0.0f;
    #pragma unroll
    for (int s = 0; s < WIN; ++s) { e[s] = __expf(p[s] - m); sum += e[s]; }
    float inv = 1.0f / sum;

    float4 acc = {0.0f, 0.0f, 0.0f, 0.0f};
    #pragma unroll
    for (int s = 0; s < WIN; ++s) {
        float ws = e[s] * inv;
        ushort4 xv = *reinterpret_cast<const ushort4*>(&Xb[(rowbase + s) * CC + u0]);
        acc.x = fmaf(ws, bf16_to_f(xv.x), acc.x);
        acc.y = fmaf(ws, bf16_to_f(xv.y), acc.y);
        acc.z = fmaf(ws, bf16_to_f(xv.z), acc.z);
        acc.w = fmaf(ws, bf16_to_f(xv.w), acc.w);
    }
    *reinterpret_cast<float4*>(&out[((size_t)n * NW + w) * CC + u0]) = acc;
}

extern "C" void kernel_launch(void* const* d_in, const int* in_sizes, int n_in,
                              void* d_out, int out_size, void* d_ws, size_t ws_size,
                              hipStream_t stream) {
    const float* x  = (const float*)d_in[0];
    const float* Wq = (const float*)d_in[1];
    const float* Wk = (const float*)d_in[2];
    const float* v  = (const float*)d_in[3];
    const float* b  = (const float*)d_in[4];
    float* out = (float*)d_out;

    const size_t MU = (size_t)MROWS * UU;      // 8.39M elems
    ushort* Kbuf = (ushort*)d_ws;
    ushort* Qbuf = Kbuf + MU;
    ushort* Xb   = Qbuf + MU;
    ushort* WkT  = Xb + MU;                    // [256][256]
    ushort* WqT  = WkT + (size_t)CC * UU;      // contiguous -> combined [512][256]

    cvt_x<<<MROWS * CC / (256 * 8), 256, 0, stream>>>(x, Xb);
    transpose_w<<<dim3(8, 8, 2), 256, 0, stream>>>(Wk, Wq, WkT, WqT);
    gemm_lds<<<1024, 256, 0, stream>>>(Xb, WkT, Kbuf, Qbuf);
    attn_smooth<<<(NB * NW) / 4, 256, 0, stream>>>(Xb, Kbuf, Qbuf, v, b, out);
}

// Round 9
// 135.988 us; speedup vs baseline: 1.1230x; 1.0713x over previous
//
#include <hip/hip_runtime.h>
#include <hip/hip_bf16.h>

#define WIN   9
#define NB    8
#define LL    4096
#define CC    256
#define UU    256
#define NW    (LL - WIN + 1)   // 4088
#define MROWS (NB * LL)        // 32768

#define BM 128
#define BK 64

typedef unsigned short ushort;
typedef __attribute__((ext_vector_type(8))) unsigned short ushort8v;
typedef __attribute__((ext_vector_type(4))) unsigned short ushort4v;
typedef __attribute__((ext_vector_type(8))) short short8v;
typedef __attribute__((ext_vector_type(4))) float f32x4;

__device__ __forceinline__ float bf16_to_f(ushort u) {
    return __uint_as_float(((unsigned int)u) << 16);
}
__device__ __forceinline__ ushort f2bf(float f) {
    __hip_bfloat16 h = __float2bfloat16(f);
    return *reinterpret_cast<ushort*>(&h);
}
__device__ __forceinline__ float fast_tanh(float x) {
    float e = __expf(2.0f * x);
    return 1.0f - 2.0f * __builtin_amdgcn_rcpf(e + 1.0f);
}

// ---------------- P0: X fp32 -> bf16 (reused by GEMM A and attn sum) ---------
__global__ __launch_bounds__(256) void cvt_x(const float* __restrict__ X,
                                             ushort* __restrict__ Xb) {
    size_t i = ((size_t)blockIdx.x * 256 + threadIdx.x) * 8;
    float4 v0 = *reinterpret_cast<const float4*>(X + i);
    float4 v1 = *reinterpret_cast<const float4*>(X + i + 4);
    ushort8v o;
    o[0] = f2bf(v0.x); o[1] = f2bf(v0.y); o[2] = f2bf(v0.z); o[3] = f2bf(v0.w);
    o[4] = f2bf(v1.x); o[5] = f2bf(v1.y); o[6] = f2bf(v1.z); o[7] = f2bf(v1.w);
    *reinterpret_cast<ushort8v*>(Xb + i) = o;
}

// ---------------- P1: W [c][u] fp32 -> WT [u][c] bf16 ------------------------
// WkT and WqT are CONTIGUOUS: combined [512][256] B^T for the GEMM.
__global__ __launch_bounds__(256) void transpose_w(const float* __restrict__ Wk,
                                                   const float* __restrict__ Wq,
                                                   ushort* __restrict__ WkT,
                                                   ushort* __restrict__ WqT) {
    const float* W = blockIdx.z ? Wq : Wk;
    ushort* O = blockIdx.z ? WqT : WkT;
    __shared__ float t[32][33];
    int c0 = blockIdx.x * 32, u0 = blockIdx.y * 32;
    int tr = threadIdx.x >> 3, tc = (threadIdx.x & 7) * 4;
    float4 v = *reinterpret_cast<const float4*>(&W[(size_t)(c0 + tr) * UU + u0 + tc]);
    t[tr][tc + 0] = v.x; t[tr][tc + 1] = v.y; t[tr][tc + 2] = v.z; t[tr][tc + 3] = v.w;
    __syncthreads();
    ushort4v o;
    #pragma unroll
    for (int i = 0; i < 4; ++i) o[i] = f2bf(t[tc + i][tr]);
    *reinterpret_cast<ushort4v*>(&O[(size_t)(u0 + tr) * CC + c0 + tc]) = o;
}

// ---------------- Kernel A: LDS MFMA GEMM, 2-phase double-buffer -------------
// [K|Q] = Xb @ WT_all^T. Combined N=512. Tile 128(M) x 128(N), BK=64.
// 256 thr = 4 waves (2Mx2N), wave tile 64x64, acc[4][4] f32x4.
// global_load_lds width=16, both-sides XOR chunk swizzle (c ^= row&7).
// T3-minimum pipeline: issue STAGE(next) before ds_read+MFMA of current.
__global__ __launch_bounds__(256, 2) void gemm_lds(const ushort* __restrict__ Xb,
                                                   const ushort* __restrict__ WTall,
                                                   ushort* __restrict__ Kout,
                                                   ushort* __restrict__ Qout) {
    const int m0 = (blockIdx.x & 255) * BM;
    const int nt = blockIdx.x >> 8;          // 0..3 -> combined cols nt*128..+127
    const int n0 = nt * 128;

    __shared__ ushort As[2][BM * BK];
    __shared__ ushort Bs[2][BM * BK];

    const int tid = threadIdx.x;
    const int wid = tid >> 6, lane = tid & 63;
    const int wr = wid >> 1, wc = wid & 1;
    const int lrow = lane & 15;
    const int lkc  = lane >> 4;              // k-chunk (8 bf16) within 32-k half

    const int srow = wid * 8 + (lane >> 3);  // 0..31 within each issue
    const int schunk = lane & 7;

    f32x4 acc[4][4] = {};

    // stage one K-tile into buffer bi
    auto stage = [&](int bi, int k0) {
        #pragma unroll
        for (int i = 0; i < 4; ++i) {
            int row = i * 32 + srow;
            int ca  = schunk ^ (row & 7);
            const ushort* srcA = Xb    + (size_t)(m0 + row) * CC + k0 + ca * 8;
            const ushort* srcB = WTall + (size_t)(n0 + row) * CC + k0 + ca * 8;
            ushort* dstA = &As[bi][i * 2048 + wid * 512];
            ushort* dstB = &Bs[bi][i * 2048 + wid * 512];
            __builtin_amdgcn_global_load_lds(
                (const __attribute__((address_space(1))) void*)srcA,
                (__attribute__((address_space(3))) void*)dstA, 16, 0, 0);
            __builtin_amdgcn_global_load_lds(
                (const __attribute__((address_space(1))) void*)srcB,
                (__attribute__((address_space(3))) void*)dstB, 16, 0, 0);
        }
    };

    stage(0, 0);
    __syncthreads();

    #pragma unroll
    for (int t = 0; t < 4; ++t) {
        const int cur = t & 1;
        if (t < 3) stage(cur ^ 1, (t + 1) * BK);   // loads fly under the MFMAs

        #pragma unroll
        for (int ks = 0; ks < 2; ++ks) {
            short8v af[4], bq[4];
            #pragma unroll
            for (int m = 0; m < 4; ++m) {
                int r = wr * 64 + m * 16 + lrow;
                int cc = ks * 4 + lkc;
                af[m] = *reinterpret_cast<const short8v*>(&As[cur][r * 64 + (cc ^ (r & 7)) * 8]);
            }
            #pragma unroll
            for (int n = 0; n < 4; ++n) {
                int r = wc * 64 + n * 16 + lrow;
                int cc = ks * 4 + lkc;
                bq[n] = *reinterpret_cast<const short8v*>(&Bs[cur][r * 64 + (cc ^ (r & 7)) * 8]);
            }
            #pragma unroll
            for (int m = 0; m < 4; ++m)
                #pragma unroll
                for (int n = 0; n < 4; ++n)
                    acc[m][n] = __builtin_amdgcn_mfma_f32_16x16x32_bf16(af[m], bq[n], acc[m][n], 0, 0, 0);
        }
        if (t < 3) __syncthreads();   // drains vmcnt -> next buffer ready
    }

    // C layout: col = lane&15, row = (lane>>4)*4 + j
    ushort* Out = (nt < 2) ? Kout : Qout;
    const int colbase = (nt & 1) * 128 + wc * 64;
    const int rowbase = m0 + wr * 64 + (lane >> 4) * 4;
    #pragma unroll
    for (int m = 0; m < 4; ++m)
        #pragma unroll
        for (int n = 0; n < 4; ++n)
            #pragma unroll
            for (int j = 0; j < 4; ++j)
                Out[(size_t)(rowbase + m * 16 + j) * UU + colbase + n * 16 + lrow] =
                    f2bf(acc[m][n][j]);
}

// ---------------- Kernel B: score -> softmax -> weighted window sum ----------
// 4 items per wave, 16 lanes per item (lane t owns u/c = t*16..t*16+15).
// Reduce over u = 4 DPP-speed xor stages (1,2,4,8) shared by 4 items.
__global__ __launch_bounds__(256) void attn_smooth(
    const ushort* __restrict__ Xb,
    const ushort* __restrict__ Kb,
    const ushort* __restrict__ Qb,
    const float* __restrict__ v,
    const float* __restrict__ b,
    float* __restrict__ out) {
    const int wave = threadIdx.x >> 6;
    const int lane = threadIdx.x & 63;
    const int g = lane >> 4;                 // item-in-wave
    const int t = lane & 15;                 // lane-in-item
    // bijective XCD remap over 2044 blocks (q=255, r=4, per m204)
    const int bid = blockIdx.x;
    const int xcd = bid & 7, o8 = bid >> 3;
    const int nb = (xcd < 4 ? xcd * 256 : 1024 + (xcd - 4) * 255) + o8;
    const int item = nb * 16 + wave * 4 + g;   // < 32704 exactly
    const int n = item / NW;
    const int w = item - n * NW;
    const int u0 = t * 16;

    const size_t rowbase = (size_t)n * LL + w;

    float bb[16], vv[16];
    #pragma unroll
    for (int i = 0; i < 4; ++i) {
        *reinterpret_cast<float4*>(&bb[i * 4]) = *reinterpret_cast<const float4*>(b + u0 + i * 4);
        *reinterpret_cast<float4*>(&vv[i * 4]) = *reinterpret_cast<const float4*>(v + u0 + i * 4);
    }

    float qb[16];
    {
        const ushort* qrow = Qb + (rowbase + WIN / 2) * UU + u0;
        ushort8v q0 = *reinterpret_cast<const ushort8v*>(qrow);
        ushort8v q1 = *reinterpret_cast<const ushort8v*>(qrow + 8);
        #pragma unroll
        for (int i = 0; i < 8; ++i) {
            qb[i]     = bf16_to_f(q0[i]) + bb[i];
            qb[8 + i] = bf16_to_f(q1[i]) + bb[8 + i];
        }
    }

    float p[WIN];
    #pragma unroll
    for (int s = 0; s < WIN; ++s) {
        const ushort* krow = Kb + (rowbase + s) * UU + u0;
        ushort8v k0 = *reinterpret_cast<const ushort8v*>(krow);
        ushort8v k1 = *reinterpret_cast<const ushort8v*>(krow + 8);
        float a = 0.0f;
        #pragma unroll
        for (int i = 0; i < 8; ++i) {
            a += vv[i]     * fast_tanh(qb[i]     + bf16_to_f(k0[i]));
            a += vv[8 + i] * fast_tanh(qb[8 + i] + bf16_to_f(k1[i]));
        }
        p[s] = a;
    }
    // 4-stage xor reduce within the 16-lane group (all DPP-range offsets)
    #pragma unroll
    for (int off = 8; off; off >>= 1)
        #pragma unroll
        for (int s = 0; s < WIN; ++s)
            p[s] += __shfl_xor(p[s], off);

    float m = p[0];
    #pragma unroll
    for (int s = 1; s < WIN; ++s) m = fmaxf(m, p[s]);
    float e[WIN];
    float sum = 0.0f;
    #pragma unroll
    for (int s = 0; s < WIN; ++s) { e[s] = __expf(p[s] - m); sum += e[s]; }
    float inv = 1.0f / sum;

    float acc[16] = {};
    #pragma unroll
    for (int s = 0; s < WIN; ++s) {
        float ws = e[s] * inv;
        const ushort* xrow = Xb + (rowbase + s) * CC + u0;
        ushort8v x0 = *reinterpret_cast<const ushort8v*>(xrow);
        ushort8v x1 = *reinterpret_cast<const ushort8v*>(xrow + 8);
        #pragma unroll
        for (int i = 0; i < 8; ++i) {
            acc[i]     = fmaf(ws, bf16_to_f(x0[i]), acc[i]);
            acc[8 + i] = fmaf(ws, bf16_to_f(x1[i]), acc[8 + i]);
        }
    }
    float* orow = out + ((size_t)n * NW + w) * CC + u0;
    #pragma unroll
    for (int i = 0; i < 4; ++i)
        *reinterpret_cast<float4*>(orow + i * 4) = *reinterpret_cast<const float4*>(&acc[i * 4]);
}

extern "C" void kernel_launch(void* const* d_in, const int* in_sizes, int n_in,
                              void* d_out, int out_size, void* d_ws, size_t ws_size,
                              hipStream_t stream) {
    const float* x  = (const float*)d_in[0];
    const float* Wq = (const float*)d_in[1];
    const float* Wk = (const float*)d_in[2];
    const float* v  = (const float*)d_in[3];
    const float* b  = (const float*)d_in[4];
    float* out = (float*)d_out;

    const size_t MU = (size_t)MROWS * UU;      // 8.39M elems
    ushort* Kbuf = (ushort*)d_ws;
    ushort* Qbuf = Kbuf + MU;
    ushort* Xb   = Qbuf + MU;
    ushort* WkT  = Xb + MU;                    // [256][256]
    ushort* WqT  = WkT + (size_t)CC * UU;      // contiguous -> combined [512][256]

    cvt_x<<<MROWS * CC / (256 * 8), 256, 0, stream>>>(x, Xb);
    transpose_w<<<dim3(8, 8, 2), 256, 0, stream>>>(Wk, Wq, WkT, WqT);
    gemm_lds<<<1024, 256, 0, stream>>>(Xb, WkT, Kbuf, Qbuf);
    attn_smooth<<<2044, 256, 0, stream>>>(Xb, Kbuf, Qbuf, v, b, out);
}